// Round 4
// baseline (378.694 us; speedup 1.0000x reference)
//
#include <hip/hip_runtime.h>
#include <math.h>

#define BB 4
#define NN 8192
#define DD 16
#define KK 32
#define OO 64
#define HALF 4096
#define QPW 4   // queries per wave (persistent top-32 lists)

typedef float f32x2 __attribute__((ext_vector_type(2)));

// Kernel 1: per (b,n) point, per o=lane:
//   y1[row,o] = sum_d W[o,d]      * x[b,d,n]
//   cc[row,o] = sum_d (W[o,D+d]-W[o,d]) * x[b,d,n]
__global__ __launch_bounds__(256) void precomp_k(
    const float* __restrict__ x, const float* __restrict__ W,
    float* __restrict__ y1, float* __restrict__ cc)
{
  const int lane = threadIdx.x & 63;
  const int wid  = blockIdx.x * (blockDim.x >> 6) + (threadIdx.x >> 6);
  const int nw   = (gridDim.x * blockDim.x) >> 6;

  float w1[DD], wd[DD];
#pragma unroll
  for (int d = 0; d < DD; ++d) {
    float a  = W[lane * (2 * DD) + d];
    float b2 = W[lane * (2 * DD) + DD + d];
    w1[d] = a;
    wd[d] = b2 - a;
  }

  for (int row = wid; row < BB * NN; row += nw) {
    const float* xp = x + ((size_t)(row >> 13)) * (DD * NN) + (row & (NN - 1));
    float a1 = 0.f, a2 = 0.f;
#pragma unroll
    for (int d = 0; d < DD; ++d) {
      float xv = xp[(size_t)d * NN];
      a1 = fmaf(w1[d], xv, a1);
      a2 = fmaf(wd[d], xv, a2);
    }
    y1[(size_t)row * OO + lane] = a1;
    cc[(size_t)row * OO + lane] = a2;
  }
}

// Kernel 2: KNN top-32 (squared distance, self included) + fused edge-conv.
// 512 blocks x 1024 threads; block = 64 consecutive queries of one batch.
// Points staged in LDS in two 4096-point halves, SoA planes (48 KiB ->
// 2 blocks/CU, 8 waves/SIMD). Each lane evaluates a PAIR of consecutive
// candidates per step using packed dual-FP32 VALU ops (v_pk_*), each half
// bit-identical to the scalar sequence -> admissions identical to R1-R3.
// Top-32 per query: rank-tracked unsorted set in lanes 0..31 (zero DS ops).
__global__ __launch_bounds__(1024, 8) void knn_k(
    const float* __restrict__ pts_g, const float* __restrict__ y1,
    const float* __restrict__ cc, float* __restrict__ out)
{
  __shared__ float Px[HALF], Py[HALF], Pz[HALF];   // 48 KiB
  const int b   = blockIdx.x >> 7;    // 128 blocks per batch
  const int blk = blockIdx.x & 127;
  const float* px = pts_g + (size_t)b * (3 * NN);

  const int lane = threadIdx.x & 63;
  const int wv   = threadIdx.x >> 6;  // 0..15
  const int q0   = blk * 64 + wv * QPW;

  // Pre-negated query coords as wave-uniform {q,q} pairs (SGPR pairs).
  f32x2 nqx[QPW], nqy[QPW], nqz[QPW];
#pragma unroll
  for (int i = 0; i < QPW; ++i) {
    const int n = q0 + i;
    const float a = -__uint_as_float((unsigned)__builtin_amdgcn_readfirstlane(
        (int)__float_as_uint(px[n])));
    const float c = -__uint_as_float((unsigned)__builtin_amdgcn_readfirstlane(
        (int)__float_as_uint(px[NN + n])));
    const float e = -__uint_as_float((unsigned)__builtin_amdgcn_readfirstlane(
        (int)__float_as_uint(px[2 * NN + n])));
    nqx[i].x = a; nqx[i].y = a;
    nqy[i].x = c; nqy[i].y = c;
    nqz[i].x = e; nqz[i].y = e;
  }

  float lv[QPW];   // list value (squared distance), lanes 0..31
  int   li[QPW];   // list index
  int   ri[QPW];   // list rank (0 best .. 31 worst); lanes>=32 park at 64+
  float thr[QPW];  // current 32nd-smallest (wave-uniform -> SGPR)
#pragma unroll
  for (int i = 0; i < QPW; ++i) {
    lv[i] = INFINITY; li[i] = 0; ri[i] = (lane < 32) ? lane : 64;
    thr[i] = INFINITY;
  }

#pragma unroll 1
  for (int half = 0; half < 2; ++half) {
    const int base = half * HALF;
    __syncthreads();                  // previous half fully consumed
    for (int i = threadIdx.x; i < HALF; i += 1024) {
      const int g = base + i;
      Px[i] = px[g]; Py[i] = px[NN + g]; Pz[i] = px[2 * NN + g];
    }
    __syncthreads();

#pragma unroll 1
    for (int j = 0; j < HALF / 128; ++j) {
      // lane's candidate pair: (base + j*128 + 2*lane, +1)
      const f32x2 pxp = *(const f32x2*)&Px[j * 128 + 2 * lane];
      const f32x2 pyp = *(const f32x2*)&Py[j * 128 + 2 * lane];
      const f32x2 pzp = *(const f32x2*)&Pz[j * 128 + 2 * lane];
#pragma unroll
      for (int qq = 0; qq < QPW; ++qq) {
        f32x2 dx, dy, dz, acc;
        asm("v_pk_add_f32 %0, %1, %2" : "=v"(dx) : "v"(pxp), "s"(nqx[qq]));
        asm("v_pk_mul_f32 %0, %1, %1" : "=v"(acc) : "v"(dx));
        asm("v_pk_add_f32 %0, %1, %2" : "=v"(dy) : "v"(pyp), "s"(nqy[qq]));
        asm("v_pk_fma_f32 %0, %1, %1, %0" : "+v"(acc) : "v"(dy));
        asm("v_pk_add_f32 %0, %1, %2" : "=v"(dz) : "v"(pzp), "s"(nqz[qq]));
        asm("v_pk_fma_f32 %0, %1, %1, %0" : "+v"(acc) : "v"(dz));

        unsigned long long imp0 = __ballot(acc.x < thr[qq]);
        unsigned long long imp1 = __ballot(acc.y < thr[qq]);
        if (imp0 | imp1) {
#pragma unroll
          for (int h = 0; h < 2; ++h) {
            unsigned long long imp = h ? imp1 : imp0;
            const float dh = h ? acc.y : acc.x;
            while (imp) {
              const int src = __ffsll(imp) - 1;
              imp &= imp - 1;
              const unsigned vu = (unsigned)__builtin_amdgcn_readlane(
                  (int)__float_as_uint(dh), src);
              // positive floats: IEEE bits monotone -> uint compare
              if (vu < __float_as_uint(thr[qq])) {
                const float v  = __uint_as_float(vu);
                const int   mi = base + j * 128 + 2 * src + h;
                unsigned long long bal = __ballot(lv[qq] <= v);
                const int pos = __popcll(bal & 0xffffffffull);
                const bool evict = (ri[qq] == 31);
                ri[qq] += (ri[qq] >= pos) ? 1 : 0;
                if (evict) { ri[qq] = pos; lv[qq] = v; li[qq] = mi; }
                unsigned long long b31 = __ballot(ri[qq] == 31);
                const int l31 = __ffsll(b31) - 1;
                thr[qq] = __uint_as_float((unsigned)__builtin_amdgcn_readlane(
                    (int)__float_as_uint(lv[qq]), l31));
              }
            }
          }
        }
      }
    }
  }

  // Fused conv epilogue: lane = output channel o; k-order irrelevant (sum).
#pragma unroll 1
  for (int qq = 0; qq < QPW; ++qq) {
    const int n = q0 + qq;
    const size_t rq = (size_t)b * NN + n;
    const float cv = cc[rq * OO + lane];
    float acc = 0.f;
#pragma unroll
    for (int k = 0; k < KK; ++k) {
      const int mk = __builtin_amdgcn_readlane(li[qq], k);
      const float t = y1[((size_t)b * NN + mk) * OO + lane] + cv;
      acc += (t >= 0.f) ? t : 0.2f * t;
    }
    out[(size_t)b * (OO * NN) + (size_t)lane * NN + n] = acc * (1.f / 32.f);
  }
}

extern "C" void kernel_launch(void* const* d_in, const int* in_sizes, int n_in,
                              void* d_out, int out_size, void* d_ws, size_t ws_size,
                              hipStream_t stream) {
  const float* points = (const float*)d_in[0];
  const float* x      = (const float*)d_in[1];
  const float* W      = (const float*)d_in[2];
  float* out = (float*)d_out;

  float* y1 = (float*)d_ws;                      // B*N*O floats = 8 MB
  float* cc = y1 + (size_t)BB * NN * OO;         // B*N*O floats = 8 MB

  hipLaunchKernelGGL(precomp_k, dim3(2048), dim3(256), 0, stream, x, W, y1, cc);
  hipLaunchKernelGGL(knn_k, dim3(512), dim3(1024), 0, stream,
                     points, y1, cc, out);
}

// Round 5
// 341.862 us; speedup vs baseline: 1.1077x; 1.1077x over previous
//
#include <hip/hip_runtime.h>
#include <math.h>

#define BB 4
#define NN 8192
#define DD 16
#define KK 32
#define OO 64
#define HALF 4096
#define QPW 4   // queries per wave (persistent top-32 lists)

// Kernel 1: per (b,n) point, per o=lane:
//   y1[row,o] = sum_d W[o,d]      * x[b,d,n]
//   cc[row,o] = sum_d (W[o,D+d]-W[o,d]) * x[b,d,n]
__global__ __launch_bounds__(256) void precomp_k(
    const float* __restrict__ x, const float* __restrict__ W,
    float* __restrict__ y1, float* __restrict__ cc)
{
  const int lane = threadIdx.x & 63;
  const int wid  = blockIdx.x * (blockDim.x >> 6) + (threadIdx.x >> 6);
  const int nw   = (gridDim.x * blockDim.x) >> 6;

  float w1[DD], wd[DD];
#pragma unroll
  for (int d = 0; d < DD; ++d) {
    float a  = W[lane * (2 * DD) + d];
    float b2 = W[lane * (2 * DD) + DD + d];
    w1[d] = a;
    wd[d] = b2 - a;
  }

  for (int row = wid; row < BB * NN; row += nw) {
    const float* xp = x + ((size_t)(row >> 13)) * (DD * NN) + (row & (NN - 1));
    float a1 = 0.f, a2 = 0.f;
#pragma unroll
    for (int d = 0; d < DD; ++d) {
      float xv = xp[(size_t)d * NN];
      a1 = fmaf(w1[d], xv, a1);
      a2 = fmaf(wd[d], xv, a2);
    }
    y1[(size_t)row * OO + lane] = a1;
    cc[(size_t)row * OO + lane] = a2;
  }
}

// Kernel 2: KNN top-32 + fused edge-conv.
// 512 blocks x 1024 threads; block = 64 consecutive queries of one batch.
// Points staged in LDS in two 4096-point halves as float4 {x,y,z,|p|^2}
// (64 KiB -> 2 blocks/CU, 8 waves/SIMD). Distance in DOT form:
//   d' = |p|^2 - 2 p.q  (= d - |q|^2, ordering identical per query)
// -> 3 fma + 1 cmp per candidate per query. Top-32 per query: rank-tracked
// unsorted set in lanes 0..31, zero DS ops; threshold re-prune is a wave
// ballot (thr is monotone non-increasing).
__global__ __launch_bounds__(1024, 8) void knn_k(
    const float* __restrict__ pts_g, const float* __restrict__ y1,
    const float* __restrict__ cc, float* __restrict__ out)
{
  __shared__ float4 P[HALF];          // 64 KiB
  const int b   = blockIdx.x >> 7;    // 128 blocks per batch
  const int blk = blockIdx.x & 127;
  const float* px = pts_g + (size_t)b * (3 * NN);

  const int lane = threadIdx.x & 63;
  const int wv   = threadIdx.x >> 6;  // 0..15
  const int q0   = blk * 64 + wv * QPW;

  // Wave-uniform -2*q coords (SGPRs via readfirstlane).
  float m2qx[QPW], m2qy[QPW], m2qz[QPW];
#pragma unroll
  for (int i = 0; i < QPW; ++i) {
    const int n = q0 + i;
    m2qx[i] = -2.f * __uint_as_float((unsigned)__builtin_amdgcn_readfirstlane(
        (int)__float_as_uint(px[n])));
    m2qy[i] = -2.f * __uint_as_float((unsigned)__builtin_amdgcn_readfirstlane(
        (int)__float_as_uint(px[NN + n])));
    m2qz[i] = -2.f * __uint_as_float((unsigned)__builtin_amdgcn_readfirstlane(
        (int)__float_as_uint(px[2 * NN + n])));
  }

  float lv[QPW];   // list value (d'), lanes 0..31
  int   li[QPW];   // list index
  int   ri[QPW];   // list rank (0 best .. 31 worst); lanes>=32 park at 64+
  float thr[QPW];  // current 32nd-smallest d' (wave-uniform -> SGPR)
#pragma unroll
  for (int i = 0; i < QPW; ++i) {
    lv[i] = INFINITY; li[i] = 0; ri[i] = (lane < 32) ? lane : 64;
    thr[i] = INFINITY;
  }

#pragma unroll 1
  for (int half = 0; half < 2; ++half) {
    const int base = half * HALF;
    __syncthreads();                  // previous half fully consumed
    for (int i = threadIdx.x; i < HALF; i += 1024) {
      const int g = base + i;
      const float a = px[g], c = px[NN + g], e = px[2 * NN + g];
      P[i] = make_float4(a, c, e, fmaf(e, e, fmaf(c, c, a * a)));
    }
    __syncthreads();

#pragma unroll 1
    for (int j = 0; j < HALF / 64; ++j) {
      const float4 p = P[j * 64 + lane];
#pragma unroll
      for (int qq = 0; qq < QPW; ++qq) {
        float t = fmaf(p.x, m2qx[qq], p.w);
        t = fmaf(p.y, m2qy[qq], t);
        t = fmaf(p.z, m2qz[qq], t);        // d' = |p|^2 - 2 p.q
        unsigned long long imp = __ballot(t < thr[qq]);
        while (imp) {
          const int src = __ffsll(imp) - 1;
          imp &= imp - 1;
          // every surviving bit is a genuine improver (re-pruned below)
          const float v = __uint_as_float((unsigned)__builtin_amdgcn_readlane(
              (int)__float_as_uint(t), src));
          const int mi = base + j * 64 + src;
          unsigned long long bal = __ballot(lv[qq] <= v);
          const int pos = __popcll(bal & 0xffffffffull);
          const bool evict = (ri[qq] == 31);
          ri[qq] += (ri[qq] >= pos) ? 1 : 0;
          if (evict) { ri[qq] = pos; lv[qq] = v; li[qq] = mi; }
          unsigned long long b31 = __ballot(ri[qq] == 31);
          const int l31 = __ffsll(b31) - 1;
          thr[qq] = __uint_as_float((unsigned)__builtin_amdgcn_readlane(
              (int)__float_as_uint(lv[qq]), l31));
          imp &= __ballot(t < thr[qq]);   // prune against tightened threshold
        }
      }
    }
  }

  // Fused conv epilogue: lane = output channel o; k-order irrelevant (sum).
#pragma unroll 1
  for (int qq = 0; qq < QPW; ++qq) {
    const int n = q0 + qq;
    const size_t rq = (size_t)b * NN + n;
    const float cv = cc[rq * OO + lane];
    float acc = 0.f;
#pragma unroll
    for (int k = 0; k < KK; ++k) {
      const int mk = __builtin_amdgcn_readlane(li[qq], k);
      const float t = y1[((size_t)b * NN + mk) * OO + lane] + cv;
      acc += (t >= 0.f) ? t : 0.2f * t;
    }
    out[(size_t)b * (OO * NN) + (size_t)lane * NN + n] = acc * (1.f / 32.f);
  }
}

extern "C" void kernel_launch(void* const* d_in, const int* in_sizes, int n_in,
                              void* d_out, int out_size, void* d_ws, size_t ws_size,
                              hipStream_t stream) {
  const float* points = (const float*)d_in[0];
  const float* x      = (const float*)d_in[1];
  const float* W      = (const float*)d_in[2];
  float* out = (float*)d_out;

  float* y1 = (float*)d_ws;                      // B*N*O floats = 8 MB
  float* cc = y1 + (size_t)BB * NN * OO;         // B*N*O floats = 8 MB

  hipLaunchKernelGGL(precomp_k, dim3(2048), dim3(256), 0, stream, x, W, y1, cc);
  hipLaunchKernelGGL(knn_k, dim3(512), dim3(1024), 0, stream,
                     points, y1, cc, out);
}

// Round 6
// 212.165 us; speedup vs baseline: 1.7849x; 1.6113x over previous
//
#include <hip/hip_runtime.h>
#include <math.h>

#define BB 4
#define NN 8192
#define DD 16
#define KK 32
#define OO 64
#define HALF 4096
#define QPW 4   // queries per wave (persistent top-32 lists)

// Kernel 1: per (b,n) point, per o=lane:
//   y1[row,o] = sum_d W[o,d]      * x[b,d,n]
//   cc[row,o] = sum_d (W[o,D+d]-W[o,d]) * x[b,d,n]
__global__ __launch_bounds__(256) void precomp_k(
    const float* __restrict__ x, const float* __restrict__ W,
    float* __restrict__ y1, float* __restrict__ cc)
{
  const int lane = threadIdx.x & 63;
  const int wid  = blockIdx.x * (blockDim.x >> 6) + (threadIdx.x >> 6);
  const int nw   = (gridDim.x * blockDim.x) >> 6;

  float w1[DD], wd[DD];
#pragma unroll
  for (int d = 0; d < DD; ++d) {
    float a  = W[lane * (2 * DD) + d];
    float b2 = W[lane * (2 * DD) + DD + d];
    w1[d] = a;
    wd[d] = b2 - a;
  }

  for (int row = wid; row < BB * NN; row += nw) {
    const float* xp = x + ((size_t)(row >> 13)) * (DD * NN) + (row & (NN - 1));
    float a1 = 0.f, a2 = 0.f;
#pragma unroll
    for (int d = 0; d < DD; ++d) {
      float xv = xp[(size_t)d * NN];
      a1 = fmaf(w1[d], xv, a1);
      a2 = fmaf(wd[d], xv, a2);
    }
    y1[(size_t)row * OO + lane] = a1;
    cc[(size_t)row * OO + lane] = a2;
  }
}

// Kernel 2: two-pass KNN top-32 + fused edge-conv.
// Pass 1: branch-free per-lane min distance -> 32nd-of-64-lane-minima is a
// certified upper bound thr0 on the true 32nd distance (subset order stat).
// Pass 2: R4's exact rank-tracked online top-32, warm-started at ulp_up(thr0)
// -> ~4.5x fewer insert events. Scan order identical to R4 => identical set.
__global__ __launch_bounds__(1024, 8) void knn_k(
    const float* __restrict__ pts_g, const float* __restrict__ y1,
    const float* __restrict__ cc, float* __restrict__ out)
{
  __shared__ float4 P[HALF];          // 64 KiB
  const int b   = blockIdx.x >> 7;    // 128 blocks per batch
  const int blk = blockIdx.x & 127;
  const float* px = pts_g + (size_t)b * (3 * NN);

  const int lane = threadIdx.x & 63;
  const int wv   = threadIdx.x >> 6;  // 0..15
  const int q0   = blk * 64 + wv * QPW;

  // Wave-uniform -2*q coords (SGPRs via readfirstlane).
  float m2qx[QPW], m2qy[QPW], m2qz[QPW];
#pragma unroll
  for (int i = 0; i < QPW; ++i) {
    const int n = q0 + i;
    m2qx[i] = -2.f * __uint_as_float((unsigned)__builtin_amdgcn_readfirstlane(
        (int)__float_as_uint(px[n])));
    m2qy[i] = -2.f * __uint_as_float((unsigned)__builtin_amdgcn_readfirstlane(
        (int)__float_as_uint(px[NN + n])));
    m2qz[i] = -2.f * __uint_as_float((unsigned)__builtin_amdgcn_readfirstlane(
        (int)__float_as_uint(px[2 * NN + n])));
  }

  // ---------------- Pass 1: per-lane min over own candidates --------------
  float minv[QPW];
#pragma unroll
  for (int i = 0; i < QPW; ++i) minv[i] = INFINITY;

#pragma unroll 1
  for (int half = 0; half < 2; ++half) {
    const int base = half * HALF;
    __syncthreads();
    for (int i = threadIdx.x; i < HALF; i += 1024) {
      const int g = base + i;
      const float a = px[g], c = px[NN + g], e = px[2 * NN + g];
      P[i] = make_float4(a, c, e, fmaf(e, e, fmaf(c, c, a * a)));
    }
    __syncthreads();
#pragma unroll 4
    for (int j = 0; j < HALF / 64; ++j) {
      const float4 p = P[j * 64 + lane];
#pragma unroll
      for (int qq = 0; qq < QPW; ++qq) {
        float t = fmaf(p.x, m2qx[qq], p.w);
        t = fmaf(p.y, m2qy[qq], t);
        t = fmaf(p.z, m2qz[qq], t);
        minv[qq] = fminf(minv[qq], t);
      }
    }
  }

  // thr0 = 32nd-smallest of the 64 lane minima (value-exact under ties),
  // then one ULP up so admission by strict '<' keeps boundary ties.
  unsigned thr0p[QPW];
#pragma unroll
  for (int qq = 0; qq < QPW; ++qq) {
    const float v = minv[qq];
    int cnt = 0;
#pragma unroll
    for (int j2 = 0; j2 < 64; ++j2) {
      const float s = __uint_as_float((unsigned)__builtin_amdgcn_readlane(
          (int)__float_as_uint(v), j2));
      cnt += (s < v) ? 1 : 0;
    }
    float cand = (cnt <= 31) ? v : -INFINITY;
#pragma unroll
    for (int m = 1; m < 64; m <<= 1) cand = fmaxf(cand, __shfl_xor(cand, m));
    unsigned u = __float_as_uint(cand);
    u = ((u << 1) == 0u) ? 1u : (((int)u >= 0) ? u + 1u : u - 1u);  // ulp_up
    thr0p[qq] = (unsigned)__builtin_amdgcn_readfirstlane((int)u);
  }

  // ---------------- Pass 2: exact warm-started online top-32 --------------
  float lv[QPW];   // list value (d'), lanes 0..31
  int   li[QPW];   // list index
  int   ri[QPW];   // list rank (0 best .. 31 worst); lanes>=32 park at 64+
  float thr[QPW];  // admission threshold (wave-uniform -> SGPR)
#pragma unroll
  for (int i = 0; i < QPW; ++i) {
    lv[i] = INFINITY; li[i] = 0; ri[i] = (lane < 32) ? lane : 64;
    thr[i] = __uint_as_float(thr0p[i]);
  }

#pragma unroll 1
  for (int half = 0; half < 2; ++half) {
    const int base = half * HALF;
    __syncthreads();                  // all pass-1 / previous reads done
    for (int i = threadIdx.x; i < HALF; i += 1024) {
      const int g = base + i;
      const float a = px[g], c = px[NN + g], e = px[2 * NN + g];
      P[i] = make_float4(a, c, e, fmaf(e, e, fmaf(c, c, a * a)));
    }
    __syncthreads();

#pragma unroll 1
    for (int j = 0; j < HALF / 64; ++j) {
      const float4 p = P[j * 64 + lane];
      float t[QPW];
      unsigned long long bal0[QPW];
#pragma unroll
      for (int qq = 0; qq < QPW; ++qq) {
        float tt = fmaf(p.x, m2qx[qq], p.w);
        tt = fmaf(p.y, m2qy[qq], tt);
        tt = fmaf(p.z, m2qz[qq], tt);        // d' = |p|^2 - 2 p.q
        t[qq] = tt;
        bal0[qq] = __ballot(tt < thr[qq]);
      }
      if ((bal0[0] | bal0[1]) | (bal0[2] | bal0[3])) {
#pragma unroll
        for (int qq = 0; qq < QPW; ++qq) {
          unsigned long long imp = bal0[qq];
          while (imp) {
            const int src = __ffsll(imp) - 1;
            imp &= imp - 1;
            const float v = __uint_as_float(
                (unsigned)__builtin_amdgcn_readlane(
                    (int)__float_as_uint(t[qq]), src));
            const int mi = base + j * 64 + src;
            unsigned long long bal = __ballot(lv[qq] <= v);
            const int pos = __popcll(bal & 0xffffffffull);
            const bool evict = (ri[qq] == 31);
            ri[qq] += (ri[qq] >= pos) ? 1 : 0;
            if (evict) { ri[qq] = pos; lv[qq] = v; li[qq] = mi; }
            unsigned long long b31 = __ballot(ri[qq] == 31);
            const int l31 = __ffsll(b31) - 1;
            const unsigned nt = (unsigned)__builtin_amdgcn_readlane(
                (int)__float_as_uint(lv[qq]), l31);
            // during fill the rank-31 slot is still INF: keep warm thr0'
            thr[qq] = __uint_as_float((nt == 0x7f800000u) ? thr0p[qq] : nt);
            imp &= __ballot(t[qq] < thr[qq]);   // prune vs tightened thr
          }
        }
      }
    }
  }

  // Fused conv epilogue: lane = output channel o; k-order irrelevant (sum).
#pragma unroll 1
  for (int qq = 0; qq < QPW; ++qq) {
    const int n = q0 + qq;
    const size_t rq = (size_t)b * NN + n;
    const float cv = cc[rq * OO + lane];
    float acc = 0.f;
#pragma unroll
    for (int k = 0; k < KK; ++k) {
      const int mk = __builtin_amdgcn_readlane(li[qq], k);
      const float t = y1[((size_t)b * NN + mk) * OO + lane] + cv;
      acc += (t >= 0.f) ? t : 0.2f * t;
    }
    out[(size_t)b * (OO * NN) + (size_t)lane * NN + n] = acc * (1.f / 32.f);
  }
}

extern "C" void kernel_launch(void* const* d_in, const int* in_sizes, int n_in,
                              void* d_out, int out_size, void* d_ws, size_t ws_size,
                              hipStream_t stream) {
  const float* points = (const float*)d_in[0];
  const float* x      = (const float*)d_in[1];
  const float* W      = (const float*)d_in[2];
  float* out = (float*)d_out;

  float* y1 = (float*)d_ws;                      // B*N*O floats = 8 MB
  float* cc = y1 + (size_t)BB * NN * OO;         // B*N*O floats = 8 MB

  hipLaunchKernelGGL(precomp_k, dim3(2048), dim3(256), 0, stream, x, W, y1, cc);
  hipLaunchKernelGGL(knn_k, dim3(512), dim3(1024), 0, stream,
                     points, y1, cc, out);
}

// Round 7
// 194.312 us; speedup vs baseline: 1.9489x; 1.0919x over previous
//
#include <hip/hip_runtime.h>
#include <math.h>

#define BB 4
#define NN 8192
#define DD 16
#define KK 32
#define OO 64
#define QTR 2048   // points staged per round (quarter of N)
#define QPW 4      // queries per wave

// ---- sortable-float helpers (monotone bijection float -> uint32) ----------
__device__ __forceinline__ unsigned encf(float f) {
  unsigned u = __float_as_uint(f);
  return ((int)u >= 0) ? (u | 0x80000000u) : ~u;
}
__device__ __forceinline__ float decf(unsigned s) {
  unsigned u = (s & 0x80000000u) ? (s & 0x7fffffffu) : ~s;
  return __uint_as_float(u);
}
__device__ __forceinline__ float ulp_up(float f) {
  unsigned u = __float_as_uint(f);
  u = ((u << 1) == 0u) ? 1u : (((int)u >= 0) ? u + 1u : u - 1u);
  return __uint_as_float(u);
}
// ---- 64-lane bitonic sorts (ascending) ------------------------------------
__device__ __forceinline__ unsigned long long bsort64(unsigned long long key,
                                                      int lane) {
#pragma unroll
  for (int k = 2; k <= 64; k <<= 1) {
#pragma unroll
    for (int j = k >> 1; j > 0; j >>= 1) {
      const unsigned long long o = __shfl_xor(key, j);
      const bool takemin = (((lane & j) == 0) == ((lane & k) == 0));
      key = takemin ? (key < o ? key : o) : (key > o ? key : o);
    }
  }
  return key;
}
__device__ __forceinline__ float bsortf(float v, int lane) {
#pragma unroll
  for (int k = 2; k <= 64; k <<= 1) {
#pragma unroll
    for (int j = k >> 1; j > 0; j >>= 1) {
      const float o = __shfl_xor(v, j);
      const bool takemin = (((lane & j) == 0) == ((lane & k) == 0));
      v = takemin ? fminf(v, o) : fmaxf(v, o);
    }
  }
  return v;
}

// Kernel 1: per (b,n) point, per o=lane:
//   y1[row,o] = sum_d W[o,d]      * x[b,d,n]
//   cc[row,o] = sum_d (W[o,D+d]-W[o,d]) * x[b,d,n]
__global__ __launch_bounds__(256) void precomp_k(
    const float* __restrict__ x, const float* __restrict__ W,
    float* __restrict__ y1, float* __restrict__ cc)
{
  const int lane = threadIdx.x & 63;
  const int wid  = blockIdx.x * (blockDim.x >> 6) + (threadIdx.x >> 6);
  const int nw   = (gridDim.x * blockDim.x) >> 6;

  float w1[DD], wd[DD];
#pragma unroll
  for (int d = 0; d < DD; ++d) {
    float a  = W[lane * (2 * DD) + d];
    float b2 = W[lane * (2 * DD) + DD + d];
    w1[d] = a;
    wd[d] = b2 - a;
  }

  for (int row = wid; row < BB * NN; row += nw) {
    const float* xp = x + ((size_t)(row >> 13)) * (DD * NN) + (row & (NN - 1));
    float a1 = 0.f, a2 = 0.f;
#pragma unroll
    for (int d = 0; d < DD; ++d) {
      float xv = xp[(size_t)d * NN];
      a1 = fmaf(w1[d], xv, a1);
      a2 = fmaf(wd[d], xv, a2);
    }
    y1[(size_t)row * OO + lane] = a1;
    cc[(size_t)row * OO + lane] = a2;
  }
}

// Kernel 2: two-pass KNN top-32 + fused edge-conv.
// Pass 1: per-lane min over its 128-candidate stripe; 32nd of the 64 lane
//   minima (bitonic sort over lanes) is a certified upper bound thr0.
// Pass 2: candidates with d' < ulp_up(thr0) are APPENDED to a per-query LDS
//   buffer (slot = cnt + mbcnt(ballot) — no atomics, no serial chains).
//   Rare overflow -> compact: bitonic-sort 64, keep top-32, tighten thr.
// Selection: one 64-lane bitonic sort of (value,idx) keys per query; lanes
//   0..31 hold the exact stable top-32 in order. Identical set/order to the
//   reference's top_k => absmax invariant vs R5.
__global__ __launch_bounds__(1024, 8) void knn_k(
    const float* __restrict__ pts_g, const float* __restrict__ y1,
    const float* __restrict__ cc, float* __restrict__ out)
{
  __shared__ float4 P[QTR];                    // 32 KiB
  __shared__ unsigned long long BUF[64][64];   // 32 KiB: [wave-query][slot]
  const int b   = blockIdx.x >> 7;    // 128 blocks per batch
  const int blk = blockIdx.x & 127;
  const float* px = pts_g + (size_t)b * (3 * NN);

  const int lane = threadIdx.x & 63;
  const int wv   = threadIdx.x >> 6;  // 0..15
  const int q0   = blk * 64 + wv * QPW;
  const int wq   = wv * QPW;          // base row in BUF

  // Wave-uniform -2*q coords.
  float m2qx[QPW], m2qy[QPW], m2qz[QPW];
#pragma unroll
  for (int i = 0; i < QPW; ++i) {
    const int n = q0 + i;
    m2qx[i] = -2.f * __uint_as_float((unsigned)__builtin_amdgcn_readfirstlane(
        (int)__float_as_uint(px[n])));
    m2qy[i] = -2.f * __uint_as_float((unsigned)__builtin_amdgcn_readfirstlane(
        (int)__float_as_uint(px[NN + n])));
    m2qz[i] = -2.f * __uint_as_float((unsigned)__builtin_amdgcn_readfirstlane(
        (int)__float_as_uint(px[2 * NN + n])));
  }

  // ---------------- Pass 1: per-lane min over own stripe ------------------
  float minv[QPW];
#pragma unroll
  for (int i = 0; i < QPW; ++i) minv[i] = INFINITY;

#pragma unroll 1
  for (int qt = 0; qt < 4; ++qt) {
    __syncthreads();
    for (int i = threadIdx.x; i < QTR; i += 1024) {
      const int g = qt * QTR + i;
      const float a = px[g], c = px[NN + g], e = px[2 * NN + g];
      P[i] = make_float4(a, c, e, fmaf(e, e, fmaf(c, c, a * a)));
    }
    __syncthreads();
#pragma unroll 4
    for (int j = 0; j < QTR / 64; ++j) {
      const float4 p = P[j * 64 + lane];
#pragma unroll
      for (int qq = 0; qq < QPW; ++qq) {
        float t = fmaf(p.x, m2qx[qq], p.w);
        t = fmaf(p.y, m2qy[qq], t);
        t = fmaf(p.z, m2qz[qq], t);
        minv[qq] = fminf(minv[qq], t);
      }
    }
  }

  // thr0 = ulp_up(32nd-smallest of 64 lane minima) via lane bitonic sort.
  float thr[QPW];
  int   cnt[QPW];
#pragma unroll
  for (int qq = 0; qq < QPW; ++qq) {
    const float s = bsortf(minv[qq], lane);
    const float v31 = __uint_as_float((unsigned)__builtin_amdgcn_readlane(
        (int)__float_as_uint(s), 31));
    thr[qq] = ulp_up(v31);
    cnt[qq] = 0;
  }

  // ---------------- Pass 2: buffered admissions ---------------------------
#pragma unroll 1
  for (int qt = 0; qt < 4; ++qt) {
    __syncthreads();
    for (int i = threadIdx.x; i < QTR; i += 1024) {
      const int g = qt * QTR + i;
      const float a = px[g], c = px[NN + g], e = px[2 * NN + g];
      P[i] = make_float4(a, c, e, fmaf(e, e, fmaf(c, c, a * a)));
    }
    __syncthreads();

#pragma unroll 1
    for (int j = 0; j < QTR / 64; ++j) {
      const float4 p = P[j * 64 + lane];
      float t[QPW];
      unsigned long long bq[QPW];
#pragma unroll
      for (int qq = 0; qq < QPW; ++qq) {
        float tt = fmaf(p.x, m2qx[qq], p.w);
        tt = fmaf(p.y, m2qy[qq], tt);
        tt = fmaf(p.z, m2qz[qq], tt);
        t[qq] = tt;
        bq[qq] = __ballot(tt < thr[qq]);
      }
      if ((bq[0] | bq[1]) | (bq[2] | bq[3])) {
        const int gbase = qt * QTR + j * 64;
#pragma unroll
        for (int qq = 0; qq < QPW; ++qq) {
          if (bq[qq]) {
            const int nadm = __popcll(bq[qq]);
            if (cnt[qq] + nadm <= 64) {
              if (t[qq] < thr[qq]) {   // admitting lanes (matches bq exactly)
                const int pos = cnt[qq] +
                    __builtin_amdgcn_mbcnt_hi((unsigned)(bq[qq] >> 32),
                        __builtin_amdgcn_mbcnt_lo((unsigned)bq[qq], 0));
                BUF[wq + qq][pos] =
                    ((unsigned long long)encf(t[qq]) << 32) |
                    (unsigned)(gbase + lane);
              }
              cnt[qq] += nadm;
            } else {
              // rare: serial append with compact-on-full (certified exact)
              unsigned long long rem = bq[qq];
              while (rem) {
                if (cnt[qq] == 64) {
                  unsigned long long ck = BUF[wq + qq][lane];
                  ck = bsort64(ck, lane);
                  if (lane < 32) BUF[wq + qq][lane] = ck;
                  cnt[qq] = 32;
                  const unsigned s31 = (unsigned)__builtin_amdgcn_readlane(
                      (int)(unsigned)(ck >> 32), 31);
                  thr[qq] = ulp_up(decf(s31));
                  rem &= __ballot(t[qq] < thr[qq]);
                  continue;
                }
                const int src = __ffsll(rem) - 1;
                rem &= rem - 1;
                if (lane == src)
                  BUF[wq + qq][cnt[qq]] =
                      ((unsigned long long)encf(t[qq]) << 32) |
                      (unsigned)(gbase + lane);
                cnt[qq] += 1;
              }
            }
          }
        }
      }
    }
  }

  // ------------- Selection (bitonic) + fused conv epilogue ----------------
#pragma unroll 1
  for (int qq = 0; qq < QPW; ++qq) {
    unsigned long long key = (lane < cnt[qq]) ? BUF[wq + qq][lane]
                                              : ~0ull;
    key = bsort64(key, lane);           // lanes 0..31: stable top-32 in order
    const int li = (int)(unsigned)(key & 0xffffffffu);

    const int n = q0 + qq;
    const size_t rq = (size_t)b * NN + n;
    const float cv = cc[rq * OO + lane];
    float acc = 0.f;
#pragma unroll
    for (int k = 0; k < KK; ++k) {
      const int mk = __builtin_amdgcn_readlane(li, k);
      const float t = y1[((size_t)b * NN + mk) * OO + lane] + cv;
      acc += (t >= 0.f) ? t : 0.2f * t;
    }
    out[(size_t)b * (OO * NN) + (size_t)lane * NN + n] = acc * (1.f / 32.f);
  }
}

extern "C" void kernel_launch(void* const* d_in, const int* in_sizes, int n_in,
                              void* d_out, int out_size, void* d_ws, size_t ws_size,
                              hipStream_t stream) {
  const float* points = (const float*)d_in[0];
  const float* x      = (const float*)d_in[1];
  const float* W      = (const float*)d_in[2];
  float* out = (float*)d_out;

  float* y1 = (float*)d_ws;                      // B*N*O floats = 8 MB
  float* cc = y1 + (size_t)BB * NN * OO;         // B*N*O floats = 8 MB

  hipLaunchKernelGGL(precomp_k, dim3(2048), dim3(256), 0, stream, x, W, y1, cc);
  hipLaunchKernelGGL(knn_k, dim3(512), dim3(1024), 0, stream,
                     points, y1, cc, out);
}